// Round 6
// baseline (464.516 us; speedup 1.0000x reference)
//
#include <hip/hip_runtime.h>
#include <hip/hip_bf16.h>
#include <math.h>

#define DMODEL 1024
#define NH     16
#define HD     64
#define FFDIM  4096
#define SEQ    1024
#define BATCH  8
#define ROWS   (BATCH * SEQ)  // 8192

typedef __bf16 bf16x8 __attribute__((ext_vector_type(8)));
typedef __bf16 bf16x4 __attribute__((ext_vector_type(4)));
typedef float  f32x4  __attribute__((ext_vector_type(4)));

__device__ __forceinline__ unsigned short f2bf(float f) {
  unsigned int u = __builtin_bit_cast(unsigned int, f);
  u += 0x7fff + ((u >> 16) & 1);
  return (unsigned short)(u >> 16);
}

__device__ __forceinline__ void gload_lds16(const void* g, void* l) {
  __builtin_amdgcn_global_load_lds(
      (const __attribute__((address_space(1))) unsigned int*)g,
      (__attribute__((address_space(3))) unsigned int*)l, 16, 0, 0);
}

// HW transpose read: 8 bf16 = rows base..base+7 (stride 32B) of a [*][16]-bf16 tile.
__device__ __forceinline__ bf16x8 tr_read8(const unsigned short* p) {
  bf16x4 lo, hi;
  const __attribute__((address_space(3))) unsigned short* p3 =
      (const __attribute__((address_space(3))) unsigned short*)p;
  asm volatile("ds_read_b64_tr_b16 %0, %2\n\t"
               "ds_read_b64_tr_b16 %1, %2 offset:128"
               : "=v"(lo), "=v"(hi)
               : "v"(p3));
  return __builtin_shufflevector(lo, hi, 0, 1, 2, 3, 4, 5, 6, 7);
}

template <int N>
__device__ __forceinline__ void wait_vm() {
  if constexpr (N == 0)
    asm volatile("s_waitcnt vmcnt(0)" ::: "memory");
  else if constexpr (N == 3)
    asm volatile("s_waitcnt vmcnt(3)" ::: "memory");
  else if constexpr (N == 4)
    asm volatile("s_waitcnt vmcnt(4)" ::: "memory");
  else if constexpr (N == 6)
    asm volatile("s_waitcnt vmcnt(6)" ::: "memory");
  else
    asm volatile("s_waitcnt vmcnt(8)" ::: "memory");
  __builtin_amdgcn_sched_barrier(0);
}

// ---------------- LayerNorm: f32 [rows][1024] -> bf16 ----------------
__global__ __launch_bounds__(256) void ln_bf16_kernel(
    const float* __restrict__ x, const float* __restrict__ g,
    const float* __restrict__ bta, unsigned short* __restrict__ out) {
  int row = blockIdx.x;
  int tid = threadIdx.x;
  int wid = tid >> 6, lane = tid & 63;
  const float4 v = ((const float4*)(x + (size_t)row * DMODEL))[tid];
  float s = v.x + v.y + v.z + v.w;
#pragma unroll
  for (int off = 32; off >= 1; off >>= 1) s += __shfl_xor(s, off, 64);
  __shared__ float red[8];
  if (lane == 0) red[wid] = s;
  __syncthreads();
  float mu = (red[0] + red[1] + red[2] + red[3]) * (1.0f / DMODEL);
  float4 d;
  d.x = v.x - mu; d.y = v.y - mu; d.z = v.z - mu; d.w = v.w - mu;
  float sq = d.x * d.x + d.y * d.y + d.z * d.z + d.w * d.w;
#pragma unroll
  for (int off = 32; off >= 1; off >>= 1) sq += __shfl_xor(sq, off, 64);
  if (lane == 0) red[4 + wid] = sq;
  __syncthreads();
  float var = (red[4] + red[5] + red[6] + red[7]) * (1.0f / DMODEL);
  float rs = rsqrtf(var + 1e-5f);
  const float4 gg = ((const float4*)g)[tid];
  const float4 bb = ((const float4*)bta)[tid];
  ushort4 o;
  o.x = f2bf(d.x * rs * gg.x + bb.x);
  o.y = f2bf(d.y * rs * gg.y + bb.y);
  o.z = f2bf(d.z * rs * gg.z + bb.z);
  o.w = f2bf(d.w * rs * gg.w + bb.w);
  ((ushort4*)(out + (size_t)row * DMODEL))[tid] = o;
}

// ------------- transpose f32 [R][C] -> bf16 [C][R], batched -------------
__global__ __launch_bounds__(256) void transpose_f2b_kernel(
    const float* __restrict__ in, unsigned short* __restrict__ out,
    int R, int C, long long ibs, long long obs) {
  __shared__ float tile[64][65];
  int b = blockIdx.z;
  int r0 = blockIdx.y * 64, c0 = blockIdx.x * 64;
  const float* ip = in + (size_t)b * ibs;
  unsigned short* op = out + (size_t)b * obs;
  int tid = threadIdx.x;
  int rl = tid >> 4, cl = (tid & 15) * 4;
#pragma unroll
  for (int it = 0; it < 4; ++it) {
    int r = it * 16 + rl;
    float4 v = *(const float4*)(ip + (size_t)(r0 + r) * C + c0 + cl);
    tile[r][cl] = v.x; tile[r][cl + 1] = v.y;
    tile[r][cl + 2] = v.z; tile[r][cl + 3] = v.w;
  }
  __syncthreads();
#pragma unroll
  for (int it = 0; it < 4; ++it) {
    int c = it * 16 + rl;
    ushort4 o;
    o.x = f2bf(tile[cl + 0][c]); o.y = f2bf(tile[cl + 1][c]);
    o.z = f2bf(tile[cl + 2][c]); o.w = f2bf(tile[cl + 3][c]);
    *(ushort4*)(op + (size_t)(c0 + c) * R + r0 + cl) = o;
  }
}

// ---- V [B*S][D] bf16 -> Vt [B*H][64][1024] (per-head transpose) ----
__global__ __launch_bounds__(256) void transpose_v_kernel(
    const unsigned short* __restrict__ V, unsigned short* __restrict__ Vt) {
  __shared__ unsigned short tile[64][68];
  int bh = blockIdx.y;
  int b = bh >> 4, h = bh & 15;
  int t0 = blockIdx.x * 64;
  int tid = threadIdx.x;
  int rl = tid >> 4, cl = (tid & 15) * 4;
  const unsigned short* ip = V + ((size_t)(b * SEQ + t0)) * DMODEL + h * HD;
#pragma unroll
  for (int it = 0; it < 4; ++it) {
    int t = it * 16 + rl;
    ushort4 v = *(const ushort4*)(ip + (size_t)t * DMODEL + cl);
    tile[t][cl] = v.x; tile[t][cl + 1] = v.y;
    tile[t][cl + 2] = v.z; tile[t][cl + 3] = v.w;
  }
  __syncthreads();
  unsigned short* op = Vt + ((size_t)bh * HD) * SEQ + t0;
#pragma unroll
  for (int it = 0; it < 4; ++it) {
    int d = it * 16 + rl;
    ushort4 o;
    o.x = tile[cl + 0][d]; o.y = tile[cl + 1][d];
    o.z = tile[cl + 2][d]; o.w = tile[cl + 3][d];
    *(ushort4*)(op + (size_t)d * SEQ + cl) = o;
  }
}

// ======= 256xBN ring-4 GEMM: C[M][N] = A[M][K] * Bt[N][K]^T =======
// 512 threads = 8 waves. BN=256: 2Mx4N waves (wave 128x64, acc 8x4).
// BN=128: 4Mx2N waves (wave 64x64, acc 4x4). BK=32.
// LDS: 4-slot ring (A 64KB + B 64/32KB). Stage t+3 each tile; counted
// vmcnt(2*LPT) before the single barrier per tile (never 0 mid-loop).
// L2 mapping: XCD x owns by in [4x, 4x+4), bx varies innermost-window.
// EPI 1:+bias+resid->f32 | 2:+bias,GELU->bf16 | 5: fused QKV routing
#define QSCALE 0.18033688f  // 0.125 * log2(e)

template <int BN, int EPI>
__global__ __launch_bounds__(512, 2) void gemma_kernel(
    const unsigned short* __restrict__ A, const unsigned short* __restrict__ Bt,
    const float* __restrict__ bias, const float* __restrict__ bias2,
    const float* __restrict__ bias3, const float* __restrict__ resid,
    unsigned short* __restrict__ outb, unsigned short* __restrict__ outb2,
    unsigned short* __restrict__ outb3, float* __restrict__ outf,
    int M, int N, int K) {
  constexpr int MREP = (BN == 256) ? 8 : 4;     // wave rows / 16
  constexpr int WM = MREP * 16;                 // 128 or 64
  constexpr int NW = BN / 64;                   // N-waves: 4 or 2
  constexpr int LPT = (BN == 256) ? 4 : 3;      // gloads per tile per thread
  constexpr int BSZB = BN * 64;                 // B bytes per ring slot
  __shared__ __align__(16) unsigned short As[4 * 256 * 32];  // 64 KB
  __shared__ __align__(16) unsigned short Bs[4 * BN * 32];   // 64/32 KB

  const int tid = threadIdx.x;
  const int wid = tid >> 6, lane = tid & 63;
  const int l15 = lane & 15, l4 = lane >> 4;
  const int wm = wid / NW, wn = wid % NW;

  // L2-aware mapping: XCD (id&7) gets contiguous 4-panel by range.
  const int id = (int)blockIdx.x;
  const int i = id >> 3;
  const int by = (id & 7) * 4 + (i & 3);
  const int bx = i >> 2;

  const size_t KBY = (size_t)K * 2;  // row bytes

  // ---- staging: thread -> row tid>>2 (0..127), chunk tid&3 of 64B row ----
  const int rS = tid >> 2;
  const int cS = (((tid & 3) ^ ((tid >> 3) & 3))) << 4;  // src pre-swizzle
  const char* gA0 = (const char*)A + (size_t)(by * 256 + rS) * KBY + cS;
  const char* gA1 = gA0 + 128 * KBY;
  const char* gB0 = (const char*)Bt + (size_t)(bx * BN + rS) * KBY + cS;
  const char* gB1 = gB0 + 128 * KBY;  // BN==256 only
  char* sA = (char*)As + tid * 16;    // + slot*16384 (+8192 rows 128..255)
  char* sB = (char*)Bs + tid * 16;    // + slot*BSZB

  // ---- ds_read frag bases: row r, phys chunk = l4 ^ ((r>>1)&3) ----
  const int fsw = (l4 ^ ((l15 >> 1) & 3)) << 4;
  const char* aRd = (const char*)As + (wm * WM + l15) * 64 + fsw;
  const char* bRd = (const char*)Bs + (wn * 64 + l15) * 64 + fsw;

  f32x4 acc[MREP][4];
  const f32x4 fz = {0.f, 0.f, 0.f, 0.f};
#pragma unroll
  for (int i2 = 0; i2 < MREP; ++i2)
#pragma unroll
    for (int j = 0; j < 4; ++j) acc[i2][j] = fz;

  const int nt = K >> 5;

#define STAGE(SLOT, T)                                                       \
  do {                                                                       \
    const size_t ko_ = (size_t)(T) * 64;                                     \
    gload_lds16(gA0 + ko_, sA + (SLOT) * 16384);                             \
    gload_lds16(gA1 + ko_, sA + (SLOT) * 16384 + 8192);                      \
    gload_lds16(gB0 + ko_, sB + (SLOT) * BSZB);                              \
    if constexpr (BN == 256) gload_lds16(gB1 + ko_, sB + (SLOT) * BSZB + 8192); \
  } while (0)

#define TILE(T, VMN, PF)                                                     \
  do {                                                                       \
    wait_vm<(VMN)>();                                                        \
    __builtin_amdgcn_s_barrier();                                            \
    __builtin_amdgcn_sched_barrier(0);                                       \
    if (PF) STAGE(((T) + 3) & 3, (T) + 3);                                   \
    {                                                                        \
      const char* aB = aRd + ((T) & 3) * 16384;                              \
      const char* bB = bRd + ((T) & 3) * BSZB;                               \
      bf16x8 av[MREP], bv[4];                                                \
      _Pragma("unroll") for (int ni = 0; ni < 4; ++ni)                       \
          bv[ni] = *(const bf16x8*)(bB + ni * 1024);                         \
      _Pragma("unroll") for (int mi = 0; mi < MREP; ++mi)                    \
          av[mi] = *(const bf16x8*)(aB + mi * 1024);                         \
      __builtin_amdgcn_s_setprio(1);                                         \
      _Pragma("unroll") for (int mi = 0; mi < MREP; ++mi)                    \
          _Pragma("unroll") for (int ni = 0; ni < 4; ++ni)                   \
              acc[mi][ni] = __builtin_amdgcn_mfma_f32_16x16x32_bf16(         \
                  av[mi], bv[ni], acc[mi][ni], 0, 0, 0);                     \
      __builtin_amdgcn_s_setprio(0);                                         \
    }                                                                        \
  } while (0)

  // prologue: stage tiles 0,1,2 into slots 0,1,2
  STAGE(0, 0);
  STAGE(1, 1);
  STAGE(2, 2);

#pragma unroll 1
  for (int t = 0; t < nt - 3; ++t) TILE(t, 2 * LPT, 1);
  TILE(nt - 3, 2 * LPT, 0);
  TILE(nt - 2, LPT, 0);
  TILE(nt - 1, 0, 0);

  // ---- epilogue ----
  if (EPI == 5) {
    // fused QKV (BN=128, NBX=24): bx 0-7 -> Q (scaled), 8-15 -> K, 16-23 -> V
    const int range = bx >> 3;
    const float* bp = (range == 0) ? bias : (range == 1) ? bias2 : bias3;
    unsigned short* op = (range == 0) ? outb : (range == 1) ? outb2 : outb3;
    const float scale = (range == 0) ? QSCALE : 1.0f;
#pragma unroll
    for (int mi = 0; mi < MREP; ++mi) {
#pragma unroll
      for (int ni = 0; ni < 4; ++ni) {
        int colL = (bx & 7) * 128 + wn * 64 + ni * 16 + l15;
        float bn = bp[colL];
#pragma unroll
        for (int jj = 0; jj < 4; ++jj) {
          int row = by * 256 + wm * WM + mi * 16 + l4 * 4 + jj;
          op[(size_t)row * 1024 + colL] = f2bf((acc[mi][ni][jj] + bn) * scale);
        }
      }
    }
  } else {
#pragma unroll
    for (int mi = 0; mi < MREP; ++mi) {
#pragma unroll
      for (int ni = 0; ni < 4; ++ni) {
        int col = bx * BN + wn * 64 + ni * 16 + l15;
        float bn = bias[col];
#pragma unroll
        for (int jj = 0; jj < 4; ++jj) {
          int row = by * 256 + wm * WM + mi * 16 + l4 * 4 + jj;
          float v = acc[mi][ni][jj] + bn;
          if (EPI == 1) {
            outf[(size_t)row * N + col] = v + resid[(size_t)row * N + col];
          } else if (EPI == 2) {
            float gel = 0.5f * v * (1.0f + erff(v * 0.70710678118f));
            outb[(size_t)row * N + col] = f2bf(gel);
          } else {
            outb[(size_t)row * N + col] = f2bf(v);
          }
        }
      }
    }
  }
#undef STAGE
#undef TILE
}

// ---------------- Flash attention (KVBLK=128, exp2 domain, tr-read PV) ----------------
// Q pre-scaled by 0.125*log2e. Grid: 2048 blocks, XCD-swizzled. 4 waves x 16 q-rows.
__global__ __launch_bounds__(256, 3) void attn_kernel(
    const unsigned short* __restrict__ Q, const unsigned short* __restrict__ K,
    const unsigned short* __restrict__ Vt, unsigned short* __restrict__ O) {
  __shared__ __align__(16) unsigned short Ks[128 * 64];   // [key][d] 128B rows, swz
  __shared__ __align__(16) unsigned short Vs[64 * 128];   // [d][key] 256B rows, swz
  __shared__ __align__(16) unsigned short Ps[4][128 * 16];  // per-wave P^T [key][q]
  int tid = threadIdx.x, wid = tid >> 6, lane = tid & 63;
  int l15 = lane & 15, l4 = lane >> 4;
  int sid = blockIdx.x;
  int aid = (sid & 7) * 256 + (sid >> 3);
  int bh = aid >> 4, qb = aid & 15;
  int b = bh >> 4, h = bh & 15;
  int q0 = qb * 64 + wid * 16;
  const f32x4 fz = {0.f, 0.f, 0.f, 0.f};

  const unsigned short* Qbase = Q + ((size_t)(b * SEQ + q0)) * DMODEL + h * HD;
  bf16x8 qf[2];
#pragma unroll
  for (int kh = 0; kh < 2; ++kh)
    qf[kh] = *(const bf16x8*)(Qbase + (size_t)l15 * DMODEL + kh * 32 + l4 * 8);

  f32x4 o[4];
#pragma unroll
  for (int i = 0; i < 4; ++i) o[i] = fz;
  float mrun[4], lrun[4];
#pragma unroll
  for (int j = 0; j < 4; ++j) { mrun[j] = -1e30f; lrun[j] = 0.0f; }

  const unsigned short* Kb = K + (size_t)b * SEQ * DMODEL + h * HD;
  const unsigned short* Vb = Vt + (size_t)bh * HD * SEQ;
  unsigned short* pbase = &Ps[wid][0];
  int krow = tid >> 3, kchunk = tid & 7;
  int vrow = tid >> 4, vchunk = tid & 15;

  for (int t0 = 0; t0 < SEQ; t0 += 128) {
    __syncthreads();
#pragma unroll
    for (int p = 0; p < 4; ++p) {
      int kr = p * 32 + krow;
      int kg = kchunk ^ (kr & 7);
      gload_lds16(Kb + (size_t)(t0 + kr) * DMODEL + kg * 8,
                  (char*)Ks + p * 4096 + tid * 16);
      int vr = p * 16 + vrow;
      int vg = vchunk ^ (vr & 7);
      gload_lds16(Vb + (size_t)vr * SEQ + t0 + vg * 8,
                  (char*)Vs + p * 4096 + tid * 16);
    }
    __syncthreads();
    f32x4 s[8];
#pragma unroll
    for (int ts = 0; ts < 8; ++ts) {
      int row = ts * 16 + l15;
      bf16x8 k0f = *(const bf16x8*)((const char*)Ks + row * 128 + ((l4) ^ (row & 7)) * 16);
      bf16x8 k1f = *(const bf16x8*)((const char*)Ks + row * 128 + ((4 + l4) ^ (row & 7)) * 16);
      s[ts] = __builtin_amdgcn_mfma_f32_16x16x32_bf16(qf[0], k0f, fz, 0, 0, 0);
      s[ts] = __builtin_amdgcn_mfma_f32_16x16x32_bf16(qf[1], k1f, s[ts], 0, 0, 0);
    }
#pragma unroll
    for (int j = 0; j < 4; ++j) {
      float tm = fmaxf(fmaxf(fmaxf(s[0][j], s[1][j]), fmaxf(s[2][j], s[3][j])),
                       fmaxf(fmaxf(s[4][j], s[5][j]), fmaxf(s[6][j], s[7][j])));
#pragma unroll
      for (int off = 8; off >= 1; off >>= 1) tm = fmaxf(tm, __shfl_xor(tm, off, 16));
      float mnew = fmaxf(mrun[j], tm);
      float alpha = __builtin_amdgcn_exp2f(mrun[j] - mnew);
      float ps = 0.0f;
#pragma unroll
      for (int ts = 0; ts < 8; ++ts) {
        float p = __builtin_amdgcn_exp2f(s[ts][j] - mnew);
        s[ts][j] = p;
        ps += p;
      }
#pragma unroll
      for (int off = 8; off >= 1; off >>= 1) ps += __shfl_xor(ps, off, 16);
      lrun[j] = lrun[j] * alpha + ps;
      mrun[j] = mnew;
#pragma unroll
      for (int d = 0; d < 4; ++d) o[d][j] *= alpha;
    }
#pragma unroll
    for (int ts = 0; ts < 8; ++ts) {
      ushort4 pk;
      pk.x = f2bf(s[ts][0]); pk.y = f2bf(s[ts][1]);
      pk.z = f2bf(s[ts][2]); pk.w = f2bf(s[ts][3]);
      *(ushort4*)((char*)pbase + (ts * 16 + l15) * 32 + l4 * 8) = pk;
    }
    asm volatile("s_waitcnt lgkmcnt(0)" ::: "memory");
    __builtin_amdgcn_sched_barrier(0);
#pragma unroll
    for (int kp = 0; kp < 4; ++kp) {
      bf16x8 pf = tr_read8(pbase + (kp * 32 + l4 * 8) * 16 + l15);
      asm volatile("s_waitcnt lgkmcnt(0)" ::: "memory");
      __builtin_amdgcn_sched_barrier(0);
#pragma unroll
      for (int d = 0; d < 4; ++d) {
        int vr = d * 16 + l15;
        int vphys = (kp * 4 + l4) ^ (vr & 7);
        bf16x8 vf = *(const bf16x8*)((const char*)Vs + vr * 256 + vphys * 16);
        o[d] = __builtin_amdgcn_mfma_f32_16x16x32_bf16(pf, vf, o[d], 0, 0, 0);
      }
    }
  }
  unsigned short* Ob = O + ((size_t)(b * SEQ + q0)) * DMODEL + h * HD;
#pragma unroll
  for (int j = 0; j < 4; ++j) {
    float inv = 1.0f / lrun[j];
#pragma unroll
    for (int d = 0; d < 4; ++d) {
      int row = l4 * 4 + j;
      Ob[(size_t)row * DMODEL + d * 16 + l15] = f2bf(o[d][j] * inv);
    }
  }
}

extern "C" void kernel_launch(void* const* d_in, const int* in_sizes, int n_in,
                              void* d_out, int out_size, void* d_ws, size_t ws_size,
                              hipStream_t stream) {
  (void)in_sizes; (void)n_in; (void)out_size; (void)ws_size;
  const float* x    = (const float*)d_in[0];
  const float* ln1g = (const float*)d_in[1];
  const float* ln1b = (const float*)d_in[2];
  const float* ln2g = (const float*)d_in[3];
  const float* ln2b = (const float*)d_in[4];
  const float* Wq   = (const float*)d_in[5];
  const float* bq   = (const float*)d_in[6];
  const float* Wk   = (const float*)d_in[7];
  const float* bk   = (const float*)d_in[8];
  const float* Wv   = (const float*)d_in[9];
  const float* bv   = (const float*)d_in[10];
  const float* Wo   = (const float*)d_in[11];
  const float* bo   = (const float*)d_in[12];
  const float* W1   = (const float*)d_in[13];
  const float* b1   = (const float*)d_in[14];
  const float* W2   = (const float*)d_in[15];
  const float* b2   = (const float*)d_in[16];
  float* out = (float*)d_out;

  char* ws = (char*)d_ws;
  const size_t MB = 1u << 20;
  unsigned short* wqT = (unsigned short*)(ws + 0 * MB);   // [1024][1024] } contiguous
  unsigned short* wkT = (unsigned short*)(ws + 2 * MB);   // [1024][1024] } = [3072][1024]
  unsigned short* wvT = (unsigned short*)(ws + 4 * MB);   // [1024][1024] }
  unsigned short* woT = (unsigned short*)(ws + 6 * MB);
  unsigned short* w1T = (unsigned short*)(ws + 8 * MB);   // [4096][1024]
  unsigned short* w2T = (unsigned short*)(ws + 16 * MB);  // [1024][4096]
  unsigned short* hb  = (unsigned short*)(ws + 24 * MB);  // LN out, bf16 [8192][1024]
  unsigned short* Qb  = (unsigned short*)(ws + 40 * MB);
  unsigned short* Kb  = (unsigned short*)(ws + 56 * MB);
  unsigned short* Vb  = (unsigned short*)(ws + 72 * MB);
  unsigned short* Vt  = (unsigned short*)(ws + 88 * MB);  // [128][64][1024]
  unsigned short* Ob  = Vb;                                // reuse V after Vt built
  unsigned short* ff1 = (unsigned short*)(ws + 40 * MB);  // [8192][4096], reuses QKV

  // weights -> bf16 transposed [N][K]
  transpose_f2b_kernel<<<dim3(1, 16, 16), 256, 0, stream>>>(Wq, wqT, 1024, 64,
                                                            65536LL, 65536LL);
  transpose_f2b_kernel<<<dim3(1, 16, 16), 256, 0, stream>>>(Wk, wkT, 1024, 64,
                                                            65536LL, 65536LL);
  transpose_f2b_kernel<<<dim3(1, 16, 16), 256, 0, stream>>>(Wv, wvT, 1024, 64,
                                                            65536LL, 65536LL);
  transpose_f2b_kernel<<<dim3(16, 16, 1), 256, 0, stream>>>(Wo, woT, 1024, 1024, 0, 0);
  transpose_f2b_kernel<<<dim3(64, 16, 1), 256, 0, stream>>>(W1, w1T, 1024, 4096, 0, 0);
  transpose_f2b_kernel<<<dim3(16, 64, 1), 256, 0, stream>>>(W2, w2T, 4096, 1024, 0, 0);

  // h = LN1(x)
  ln_bf16_kernel<<<dim3(ROWS), 256, 0, stream>>>(x, ln1g, ln1b, hb);

  // fused QKV projection (BN=128, NBX=24; Q pre-scaled for exp2 softmax)
  gemma_kernel<128, 5><<<dim3(768), 512, 0, stream>>>(
      hb, wqT, bq, bk, bv, nullptr, Qb, Kb, Vb, nullptr, ROWS, 1024, DMODEL);

  // V -> Vt per (b,h)
  transpose_v_kernel<<<dim3(16, 128), 256, 0, stream>>>(Vb, Vt);

  // attention -> O (concat-head layout), XCD-swizzled 1D grid
  attn_kernel<<<dim3(2048), 256, 0, stream>>>(Qb, Kb, Vt, Ob);

  // x2 = x + O @ Wo + bo   (f32, stored in d_out)
  gemma_kernel<128, 1><<<dim3(256), 512, 0, stream>>>(
      Ob, woT, bo, nullptr, nullptr, x, nullptr, nullptr, nullptr, out,
      ROWS, DMODEL, DMODEL);

  // h2 = LN2(x2)
  ln_bf16_kernel<<<dim3(ROWS), 256, 0, stream>>>(out, ln2g, ln2b, hb);

  // ff1 = gelu(h2 @ W1 + b1)  (BN=256)
  gemma_kernel<256, 2><<<dim3(512), 512, 0, stream>>>(
      hb, w1T, b1, nullptr, nullptr, nullptr, ff1, nullptr, nullptr, nullptr,
      ROWS, FFDIM, DMODEL);

  // out = x2 + ff1 @ W2 + b2
  gemma_kernel<128, 1><<<dim3(256), 512, 0, stream>>>(
      ff1, w2T, b2, nullptr, nullptr, out, nullptr, nullptr, nullptr, out,
      ROWS, DMODEL, FFDIM);
}

// Round 7
// 392.836 us; speedup vs baseline: 1.1825x; 1.1825x over previous
//
#include <hip/hip_runtime.h>
#include <hip/hip_bf16.h>
#include <math.h>

#define DMODEL 1024
#define NH     16
#define HD     64
#define FFDIM  4096
#define SEQ    1024
#define BATCH  8
#define ROWS   (BATCH * SEQ)  // 8192

typedef __bf16 bf16x8 __attribute__((ext_vector_type(8)));
typedef __bf16 bf16x4 __attribute__((ext_vector_type(4)));
typedef float  f32x4  __attribute__((ext_vector_type(4)));

__device__ __forceinline__ unsigned short f2bf(float f) {
  unsigned int u = __builtin_bit_cast(unsigned int, f);
  u += 0x7fff + ((u >> 16) & 1);
  return (unsigned short)(u >> 16);
}

__device__ __forceinline__ void gload_lds16(const void* g, void* l) {
  __builtin_amdgcn_global_load_lds(
      (const __attribute__((address_space(1))) unsigned int*)g,
      (__attribute__((address_space(3))) unsigned int*)l, 16, 0, 0);
}

// HW transpose read: 8 bf16 = rows base..base+7 (stride 32B) of a [*][16]-bf16 tile.
__device__ __forceinline__ bf16x8 tr_read8(const unsigned short* p) {
  bf16x4 lo, hi;
  const __attribute__((address_space(3))) unsigned short* p3 =
      (const __attribute__((address_space(3))) unsigned short*)p;
  asm volatile("ds_read_b64_tr_b16 %0, %2\n\t"
               "ds_read_b64_tr_b16 %1, %2 offset:128"
               : "=v"(lo), "=v"(hi)
               : "v"(p3));
  return __builtin_shufflevector(lo, hi, 0, 1, 2, 3, 4, 5, 6, 7);
}

// ---------------- LayerNorm: f32 [rows][1024] -> bf16 ----------------
__global__ __launch_bounds__(256) void ln_bf16_kernel(
    const float* __restrict__ x, const float* __restrict__ g,
    const float* __restrict__ bta, unsigned short* __restrict__ out) {
  int row = blockIdx.x;
  int tid = threadIdx.x;
  int wid = tid >> 6, lane = tid & 63;
  const float4 v = ((const float4*)(x + (size_t)row * DMODEL))[tid];
  float s = v.x + v.y + v.z + v.w;
#pragma unroll
  for (int off = 32; off >= 1; off >>= 1) s += __shfl_xor(s, off, 64);
  __shared__ float red[8];
  if (lane == 0) red[wid] = s;
  __syncthreads();
  float mu = (red[0] + red[1] + red[2] + red[3]) * (1.0f / DMODEL);
  float4 d;
  d.x = v.x - mu; d.y = v.y - mu; d.z = v.z - mu; d.w = v.w - mu;
  float sq = d.x * d.x + d.y * d.y + d.z * d.z + d.w * d.w;
#pragma unroll
  for (int off = 32; off >= 1; off >>= 1) sq += __shfl_xor(sq, off, 64);
  if (lane == 0) red[4 + wid] = sq;
  __syncthreads();
  float var = (red[4] + red[5] + red[6] + red[7]) * (1.0f / DMODEL);
  float rs = rsqrtf(var + 1e-5f);
  const float4 gg = ((const float4*)g)[tid];
  const float4 bb = ((const float4*)bta)[tid];
  ushort4 o;
  o.x = f2bf(d.x * rs * gg.x + bb.x);
  o.y = f2bf(d.y * rs * gg.y + bb.y);
  o.z = f2bf(d.z * rs * gg.z + bb.z);
  o.w = f2bf(d.w * rs * gg.w + bb.w);
  ((ushort4*)(out + (size_t)row * DMODEL))[tid] = o;
}

// ------------- transpose f32 [R][C] -> bf16 [C][R], batched -------------
__global__ __launch_bounds__(256) void transpose_f2b_kernel(
    const float* __restrict__ in, unsigned short* __restrict__ out,
    int R, int C, long long ibs, long long obs) {
  __shared__ float tile[64][65];
  int b = blockIdx.z;
  int r0 = blockIdx.y * 64, c0 = blockIdx.x * 64;
  const float* ip = in + (size_t)b * ibs;
  unsigned short* op = out + (size_t)b * obs;
  int tid = threadIdx.x;
  int rl = tid >> 4, cl = (tid & 15) * 4;
#pragma unroll
  for (int it = 0; it < 4; ++it) {
    int r = it * 16 + rl;
    float4 v = *(const float4*)(ip + (size_t)(r0 + r) * C + c0 + cl);
    tile[r][cl] = v.x; tile[r][cl + 1] = v.y;
    tile[r][cl + 2] = v.z; tile[r][cl + 3] = v.w;
  }
  __syncthreads();
#pragma unroll
  for (int it = 0; it < 4; ++it) {
    int c = it * 16 + rl;
    ushort4 o;
    o.x = f2bf(tile[cl + 0][c]); o.y = f2bf(tile[cl + 1][c]);
    o.z = f2bf(tile[cl + 2][c]); o.w = f2bf(tile[cl + 3][c]);
    *(ushort4*)(op + (size_t)(c0 + c) * R + r0 + cl) = o;
  }
}

// ---- V [B*S][D] bf16 -> Vt [B*H][64][1024] (per-head transpose) ----
__global__ __launch_bounds__(256) void transpose_v_kernel(
    const unsigned short* __restrict__ V, unsigned short* __restrict__ Vt) {
  __shared__ unsigned short tile[64][68];
  int bh = blockIdx.y;
  int b = bh >> 4, h = bh & 15;
  int t0 = blockIdx.x * 64;
  int tid = threadIdx.x;
  int rl = tid >> 4, cl = (tid & 15) * 4;
  const unsigned short* ip = V + ((size_t)(b * SEQ + t0)) * DMODEL + h * HD;
#pragma unroll
  for (int it = 0; it < 4; ++it) {
    int t = it * 16 + rl;
    ushort4 v = *(const ushort4*)(ip + (size_t)t * DMODEL + cl);
    tile[t][cl] = v.x; tile[t][cl + 1] = v.y;
    tile[t][cl + 2] = v.z; tile[t][cl + 3] = v.w;
  }
  __syncthreads();
  unsigned short* op = Vt + ((size_t)bh * HD) * SEQ + t0;
#pragma unroll
  for (int it = 0; it < 4; ++it) {
    int d = it * 16 + rl;
    ushort4 o;
    o.x = tile[cl + 0][d]; o.y = tile[cl + 1][d];
    o.z = tile[cl + 2][d]; o.w = tile[cl + 3][d];
    *(ushort4*)(op + (size_t)d * SEQ + cl) = o;
  }
}

// ============ 128x128 dbuf GEMM: C[M][N] = A[M][K] * Bt[N][K]^T ============
// 512 threads = 8 waves (4M x 2N), wave tile 32x64, BK=64, LDS 64KB (dbuf),
// 2 blocks/CU = 16 waves/CU. One barrier + own-wave vmcnt(0) drain per K-tile.
// L2 superblock mapping: each XCD's ~64 concurrent blocks form an 8by x 8bx
// window (2MB A + 2MB B = 4MB = one L2); consecutive superblocks on an XCD
// share the by-range so A stays L2-resident.
// EPI 1:+bias+resid->f32 | 2:+bias,GELU->bf16 | 5: fused QKV routing
#define QSCALE 0.18033688f  // 0.125 * log2(e)

template <int EPI>
__global__ __launch_bounds__(512, 4) void gemmdb_kernel(
    const unsigned short* __restrict__ A, const unsigned short* __restrict__ Bt,
    const float* __restrict__ bias, const float* __restrict__ bias2,
    const float* __restrict__ bias3, const float* __restrict__ resid,
    unsigned short* __restrict__ outb, unsigned short* __restrict__ outb2,
    unsigned short* __restrict__ outb3, float* __restrict__ outf,
    int M, int N, int K, int NX) {
  __shared__ __align__(16) unsigned short As[2 * 128 * 64];  // 32 KB
  __shared__ __align__(16) unsigned short Bs[2 * 128 * 64];  // 32 KB

  const int tid = threadIdx.x;
  const int wid = tid >> 6, lane = tid & 63;
  const int l15 = lane & 15, l4 = lane >> 4;
  const int wm = wid >> 1, wn = wid & 1;  // 4 M-waves x 2 N-waves

  // ---- L2 superblock mapping ----
  const int id = (int)blockIdx.x;
  const int xcd = id & 7, j = id >> 3;
  const int w = j >> 6, l = j & 63;               // superblock seq, local 8x8
  const int spx = (int)gridDim.x >> 9;            // superblocks per XCD
  const int nbx8 = NX >> 3;
  const int g = xcd * spx + w;
  const int by = (g / nbx8) * 8 + (l >> 3);
  const int bx = (g % nbx8) * 8 + (l & 7);

  const size_t KBY = (size_t)K * 2;  // row bytes

  // staging: thread covers rows rS and rS+64, 16B chunk tid&7 (pre-swizzled src)
  const int rS = tid >> 3;                      // 0..63
  const int cS = ((tid & 7) ^ (rS & 7)) << 4;   // swizzle invariant under +64 rows
  const char* gA = (const char*)A + (size_t)(by * 128 + rS) * KBY + cS;
  const char* gB = (const char*)Bt + (size_t)(bx * 128 + rS) * KBY + cS;
  char* sA = (char*)As + tid * 16;  // rows 0..63 linear; +8192 rows 64..127
  char* sB = (char*)Bs + tid * 16;

  // ds_read bases: row&7 == l15&7 for all fragment rows; kk=1 flips byte-bit 6
  const int rsw = (l4 ^ (l15 & 7)) << 4;
  const char* aRd0 = (const char*)As + (wm * 32 + l15) * 128 + rsw;
  const char* aRd1 = (const char*)As + (wm * 32 + l15) * 128 + (rsw ^ 64);
  const char* bRd0 = (const char*)Bs + (wn * 64 + l15) * 128 + rsw;
  const char* bRd1 = (const char*)Bs + (wn * 64 + l15) * 128 + (rsw ^ 64);

  f32x4 acc[2][4];
  const f32x4 fz = {0.f, 0.f, 0.f, 0.f};
#pragma unroll
  for (int i = 0; i < 2; ++i)
#pragma unroll
    for (int j2 = 0; j2 < 4; ++j2) acc[i][j2] = fz;

  const int nt = K >> 6;

  // prologue: stage tile 0 into buf 0
  gload_lds16(gA, sA);
  gload_lds16(gA + 64 * KBY, sA + 8192);
  gload_lds16(gB, sB);
  gload_lds16(gB + 64 * KBY, sB + 8192);
  asm volatile("s_waitcnt vmcnt(0)" ::: "memory");
  __builtin_amdgcn_sched_barrier(0);
  __builtin_amdgcn_s_barrier();
  __builtin_amdgcn_sched_barrier(0);

#pragma unroll 1
  for (int t = 0; t < nt; ++t) {
    const int cur = t & 1;
    if (t + 1 < nt) {
      const size_t ko = (size_t)(t + 1) << 7;
      const int nb = (cur ^ 1) << 14;  // 16384 bytes per buffer
      gload_lds16(gA + ko, sA + nb);
      gload_lds16(gA + 64 * KBY + ko, sA + nb + 8192);
      gload_lds16(gB + ko, sB + nb);
      gload_lds16(gB + 64 * KBY + ko, sB + nb + 8192);
    }
    const int off = cur << 14;
#pragma unroll
    for (int kk = 0; kk < 2; ++kk) {
      const char* aR = (kk ? aRd1 : aRd0) + off;
      const char* bR = (kk ? bRd1 : bRd0) + off;
      bf16x8 afr[2], bfr[4];
#pragma unroll
      for (int ni = 0; ni < 4; ++ni) bfr[ni] = *(const bf16x8*)(bR + ni * 2048);
#pragma unroll
      for (int mi = 0; mi < 2; ++mi) afr[mi] = *(const bf16x8*)(aR + mi * 2048);
      __builtin_amdgcn_s_setprio(1);
#pragma unroll
      for (int mi = 0; mi < 2; ++mi)
#pragma unroll
        for (int ni = 0; ni < 4; ++ni)
          acc[mi][ni] = __builtin_amdgcn_mfma_f32_16x16x32_bf16(
              afr[mi], bfr[ni], acc[mi][ni], 0, 0, 0);
      __builtin_amdgcn_s_setprio(0);
    }
    asm volatile("s_waitcnt vmcnt(0)" ::: "memory");  // own-wave stage drained
    __builtin_amdgcn_sched_barrier(0);
    __builtin_amdgcn_s_barrier();
    __builtin_amdgcn_sched_barrier(0);
  }

  // ---- epilogue ----
  if (EPI == 5) {
    // fused QKV: bx 0-7 -> Q (scaled), 8-15 -> K, 16-23 -> V
    const int range = bx >> 3;
    const float* bp = (range == 0) ? bias : (range == 1) ? bias2 : bias3;
    unsigned short* op = (range == 0) ? outb : (range == 1) ? outb2 : outb3;
    const float scale = (range == 0) ? QSCALE : 1.0f;
#pragma unroll
    for (int mi = 0; mi < 2; ++mi) {
#pragma unroll
      for (int ni = 0; ni < 4; ++ni) {
        int colL = (bx & 7) * 128 + wn * 64 + ni * 16 + l15;
        float bn = bp[colL];
#pragma unroll
        for (int jj = 0; jj < 4; ++jj) {
          int row = by * 128 + wm * 32 + mi * 16 + l4 * 4 + jj;
          op[(size_t)row * 1024 + colL] = f2bf((acc[mi][ni][jj] + bn) * scale);
        }
      }
    }
  } else {
#pragma unroll
    for (int mi = 0; mi < 2; ++mi) {
#pragma unroll
      for (int ni = 0; ni < 4; ++ni) {
        int col = bx * 128 + wn * 64 + ni * 16 + l15;
        float bn = bias[col];
#pragma unroll
        for (int jj = 0; jj < 4; ++jj) {
          int row = by * 128 + wm * 32 + mi * 16 + l4 * 4 + jj;
          float v = acc[mi][ni][jj] + bn;
          if (EPI == 1) {
            outf[(size_t)row * N + col] = v + resid[(size_t)row * N + col];
          } else if (EPI == 2) {
            float gel = 0.5f * v * (1.0f + erff(v * 0.70710678118f));
            outb[(size_t)row * N + col] = f2bf(gel);
          } else {
            outb[(size_t)row * N + col] = f2bf(v);
          }
        }
      }
    }
  }
}

// ---------------- Flash attention (KVBLK=128, exp2 domain, tr-read PV) ----------------
// Q pre-scaled by 0.125*log2e. Grid: 2048 blocks, XCD-swizzled. 4 waves x 16 q-rows.
__global__ __launch_bounds__(256, 3) void attn_kernel(
    const unsigned short* __restrict__ Q, const unsigned short* __restrict__ K,
    const unsigned short* __restrict__ Vt, unsigned short* __restrict__ O) {
  __shared__ __align__(16) unsigned short Ks[128 * 64];   // [key][d] 128B rows, swz
  __shared__ __align__(16) unsigned short Vs[64 * 128];   // [d][key] 256B rows, swz
  __shared__ __align__(16) unsigned short Ps[4][128 * 16];  // per-wave P^T [key][q]
  int tid = threadIdx.x, wid = tid >> 6, lane = tid & 63;
  int l15 = lane & 15, l4 = lane >> 4;
  int sid = blockIdx.x;
  int aid = (sid & 7) * 256 + (sid >> 3);
  int bh = aid >> 4, qb = aid & 15;
  int b = bh >> 4, h = bh & 15;
  int q0 = qb * 64 + wid * 16;
  const f32x4 fz = {0.f, 0.f, 0.f, 0.f};

  const unsigned short* Qbase = Q + ((size_t)(b * SEQ + q0)) * DMODEL + h * HD;
  bf16x8 qf[2];
#pragma unroll
  for (int kh = 0; kh < 2; ++kh)
    qf[kh] = *(const bf16x8*)(Qbase + (size_t)l15 * DMODEL + kh * 32 + l4 * 8);

  f32x4 o[4];
#pragma unroll
  for (int i = 0; i < 4; ++i) o[i] = fz;
  float mrun[4], lrun[4];
#pragma unroll
  for (int j = 0; j < 4; ++j) { mrun[j] = -1e30f; lrun[j] = 0.0f; }

  const unsigned short* Kb = K + (size_t)b * SEQ * DMODEL + h * HD;
  const unsigned short* Vb = Vt + (size_t)bh * HD * SEQ;
  unsigned short* pbase = &Ps[wid][0];
  int krow = tid >> 3, kchunk = tid & 7;
  int vrow = tid >> 4, vchunk = tid & 15;

  for (int t0 = 0; t0 < SEQ; t0 += 128) {
    __syncthreads();
#pragma unroll
    for (int p = 0; p < 4; ++p) {
      int kr = p * 32 + krow;
      int kg = kchunk ^ (kr & 7);
      gload_lds16(Kb + (size_t)(t0 + kr) * DMODEL + kg * 8,
                  (char*)Ks + p * 4096 + tid * 16);
      int vr = p * 16 + vrow;
      int vg = vchunk ^ (vr & 7);
      gload_lds16(Vb + (size_t)vr * SEQ + t0 + vg * 8,
                  (char*)Vs + p * 4096 + tid * 16);
    }
    __syncthreads();
    f32x4 s[8];
#pragma unroll
    for (int ts = 0; ts < 8; ++ts) {
      int row = ts * 16 + l15;
      bf16x8 k0f = *(const bf16x8*)((const char*)Ks + row * 128 + ((l4) ^ (row & 7)) * 16);
      bf16x8 k1f = *(const bf16x8*)((const char*)Ks + row * 128 + ((4 + l4) ^ (row & 7)) * 16);
      s[ts] = __builtin_amdgcn_mfma_f32_16x16x32_bf16(qf[0], k0f, fz, 0, 0, 0);
      s[ts] = __builtin_amdgcn_mfma_f32_16x16x32_bf16(qf[1], k1f, s[ts], 0, 0, 0);
    }
#pragma unroll
    for (int j = 0; j < 4; ++j) {
      float tm = fmaxf(fmaxf(fmaxf(s[0][j], s[1][j]), fmaxf(s[2][j], s[3][j])),
                       fmaxf(fmaxf(s[4][j], s[5][j]), fmaxf(s[6][j], s[7][j])));
#pragma unroll
      for (int off = 8; off >= 1; off >>= 1) tm = fmaxf(tm, __shfl_xor(tm, off, 16));
      float mnew = fmaxf(mrun[j], tm);
      float alpha = __builtin_amdgcn_exp2f(mrun[j] - mnew);
      float ps = 0.0f;
#pragma unroll
      for (int ts = 0; ts < 8; ++ts) {
        float p = __builtin_amdgcn_exp2f(s[ts][j] - mnew);
        s[ts][j] = p;
        ps += p;
      }
#pragma unroll
      for (int off = 8; off >= 1; off >>= 1) ps += __shfl_xor(ps, off, 16);
      lrun[j] = lrun[j] * alpha + ps;
      mrun[j] = mnew;
#pragma unroll
      for (int d = 0; d < 4; ++d) o[d][j] *= alpha;
    }
#pragma unroll
    for (int ts = 0; ts < 8; ++ts) {
      ushort4 pk;
      pk.x = f2bf(s[ts][0]); pk.y = f2bf(s[ts][1]);
      pk.z = f2bf(s[ts][2]); pk.w = f2bf(s[ts][3]);
      *(ushort4*)((char*)pbase + (ts * 16 + l15) * 32 + l4 * 8) = pk;
    }
    asm volatile("s_waitcnt lgkmcnt(0)" ::: "memory");
    __builtin_amdgcn_sched_barrier(0);
#pragma unroll
    for (int kp = 0; kp < 4; ++kp) {
      bf16x8 pf = tr_read8(pbase + (kp * 32 + l4 * 8) * 16 + l15);
      asm volatile("s_waitcnt lgkmcnt(0)" ::: "memory");
      __builtin_amdgcn_sched_barrier(0);
#pragma unroll
      for (int d = 0; d < 4; ++d) {
        int vr = d * 16 + l15;
        int vphys = (kp * 4 + l4) ^ (vr & 7);
        bf16x8 vf = *(const bf16x8*)((const char*)Vs + vr * 256 + vphys * 16);
        o[d] = __builtin_amdgcn_mfma_f32_16x16x32_bf16(pf, vf, o[d], 0, 0, 0);
      }
    }
  }
  unsigned short* Ob = O + ((size_t)(b * SEQ + q0)) * DMODEL + h * HD;
#pragma unroll
  for (int j = 0; j < 4; ++j) {
    float inv = 1.0f / lrun[j];
#pragma unroll
    for (int d = 0; d < 4; ++d) {
      int row = l4 * 4 + j;
      Ob[(size_t)row * DMODEL + d * 16 + l15] = f2bf(o[d][j] * inv);
    }
  }
}

extern "C" void kernel_launch(void* const* d_in, const int* in_sizes, int n_in,
                              void* d_out, int out_size, void* d_ws, size_t ws_size,
                              hipStream_t stream) {
  (void)in_sizes; (void)n_in; (void)out_size; (void)ws_size;
  const float* x    = (const float*)d_in[0];
  const float* ln1g = (const float*)d_in[1];
  const float* ln1b = (const float*)d_in[2];
  const float* ln2g = (const float*)d_in[3];
  const float* ln2b = (const float*)d_in[4];
  const float* Wq   = (const float*)d_in[5];
  const float* bq   = (const float*)d_in[6];
  const float* Wk   = (const float*)d_in[7];
  const float* bk   = (const float*)d_in[8];
  const float* Wv   = (const float*)d_in[9];
  const float* bv   = (const float*)d_in[10];
  const float* Wo   = (const float*)d_in[11];
  const float* bo   = (const float*)d_in[12];
  const float* W1   = (const float*)d_in[13];
  const float* b1   = (const float*)d_in[14];
  const float* W2   = (const float*)d_in[15];
  const float* b2   = (const float*)d_in[16];
  float* out = (float*)d_out;

  char* ws = (char*)d_ws;
  const size_t MB = 1u << 20;
  unsigned short* wqT = (unsigned short*)(ws + 0 * MB);   // [1024][1024] } contiguous
  unsigned short* wkT = (unsigned short*)(ws + 2 * MB);   // [1024][1024] } = [3072][1024]
  unsigned short* wvT = (unsigned short*)(ws + 4 * MB);   // [1024][1024] }
  unsigned short* woT = (unsigned short*)(ws + 6 * MB);
  unsigned short* w1T = (unsigned short*)(ws + 8 * MB);   // [4096][1024]
  unsigned short* w2T = (unsigned short*)(ws + 16 * MB);  // [1024][4096]
  unsigned short* hb  = (unsigned short*)(ws + 24 * MB);  // LN out, bf16 [8192][1024]
  unsigned short* Qb  = (unsigned short*)(ws + 40 * MB);
  unsigned short* Kb  = (unsigned short*)(ws + 56 * MB);
  unsigned short* Vb  = (unsigned short*)(ws + 72 * MB);
  unsigned short* Vt  = (unsigned short*)(ws + 88 * MB);  // [128][64][1024]
  unsigned short* Ob  = Vb;                                // reuse V after Vt built
  unsigned short* ff1 = (unsigned short*)(ws + 40 * MB);  // [8192][4096], reuses QKV

  // weights -> bf16 transposed [N][K]
  transpose_f2b_kernel<<<dim3(1, 16, 16), 256, 0, stream>>>(Wq, wqT, 1024, 64,
                                                            65536LL, 65536LL);
  transpose_f2b_kernel<<<dim3(1, 16, 16), 256, 0, stream>>>(Wk, wkT, 1024, 64,
                                                            65536LL, 65536LL);
  transpose_f2b_kernel<<<dim3(1, 16, 16), 256, 0, stream>>>(Wv, wvT, 1024, 64,
                                                            65536LL, 65536LL);
  transpose_f2b_kernel<<<dim3(16, 16, 1), 256, 0, stream>>>(Wo, woT, 1024, 1024, 0, 0);
  transpose_f2b_kernel<<<dim3(64, 16, 1), 256, 0, stream>>>(W1, w1T, 1024, 4096, 0, 0);
  transpose_f2b_kernel<<<dim3(16, 64, 1), 256, 0, stream>>>(W2, w2T, 4096, 1024, 0, 0);

  // h = LN1(x)
  ln_bf16_kernel<<<dim3(ROWS), 256, 0, stream>>>(x, ln1g, ln1b, hb);

  // fused QKV projection: N=3072 (Q pre-scaled for exp2 softmax)
  gemmdb_kernel<5><<<dim3(1536), 512, 0, stream>>>(
      hb, wqT, bq, bk, bv, nullptr, Qb, Kb, Vb, nullptr, ROWS, 1024, DMODEL, 24);

  // V -> Vt per (b,h)
  transpose_v_kernel<<<dim3(16, 128), 256, 0, stream>>>(Vb, Vt);

  // attention -> O (concat-head layout), XCD-swizzled 1D grid
  attn_kernel<<<dim3(2048), 256, 0, stream>>>(Qb, Kb, Vt, Ob);

  // x2 = x + O @ Wo + bo   (f32, stored in d_out)
  gemmdb_kernel<1><<<dim3(512), 512, 0, stream>>>(
      Ob, woT, bo, nullptr, nullptr, x, nullptr, nullptr, nullptr, out,
      ROWS, DMODEL, DMODEL, 8);

  // h2 = LN2(x2)
  ln_bf16_kernel<<<dim3(ROWS), 256, 0, stream>>>(out, ln2g, ln2b, hb);

  // ff1 = gelu(h2 @ W1 + b1)
  gemmdb_kernel<2><<<dim3(2048), 512, 0, stream>>>(
      hb, w1T, b1, nullptr, nullptr, nullptr, ff1, nullptr, nullptr, nullptr,
      ROWS, FFDIM, DMODEL, 32);

  // out = x2 + ff1 @ W2 + b2
  gemmdb_kernel<1><<<dim3(512), 512, 0, stream>>>(
      ff1, w2T, b2, nullptr, nullptr, out, nullptr, nullptr, nullptr, out,
      ROWS, DMODEL, FFDIM, 8);
}